// Round 5
// baseline (446.519 us; speedup 1.0000x reference)
//
#include <hip/hip_runtime.h>

typedef unsigned short ushort_t;

#define Bb 32
#define Hh 256
#define Ll 2048
#define Nn 64
#define BHL 16777216

typedef __bf16 bf16x8 __attribute__((ext_vector_type(8)));
typedef float f32x4 __attribute__((ext_vector_type(4)));
typedef unsigned int uint4v __attribute__((ext_vector_type(4)));
typedef unsigned int uint2v __attribute__((ext_vector_type(2)));

__device__ __forceinline__ ushort_t f2bf(float f) {
    unsigned int u = __float_as_uint(f);
    unsigned int r = ((u >> 16) & 1u) + 0x7fffu;
    return (ushort_t)((u + r) >> 16);
}
__device__ __forceinline__ float bf2f(ushort_t h) {
    return __uint_as_float(((unsigned int)h) << 16);
}
__device__ __forceinline__ float gelu_tanh(float v) {
    float u = 0.7978845608028654f * fmaf(0.044715f * v, v * v, v);
    float e = __expf(2.f * u);
    float th = 1.f - 2.f / (e + 1.f);
    return 0.5f * v * (1.f + th);
}
__device__ __forceinline__ float gate_fn(float v) {
    float sg = 1.f / (1.f + __expf(-v));
    float e2 = __expf(2.f * v);
    float th = 1.f - 2.f / (e2 + 1.f);
    return th * sg;
}
__device__ __forceinline__ uint4v rev8v(uint4v a) {
    union { uint4v v; ushort_t s8[8]; } x, y;
    x.v = a;
    #pragma unroll
    for (int j = 0; j < 8; ++j) y.s8[j] = x.s8[7 - j];
    return y.v;
}

// ---------------- prep_all: tb GEMM + weight repack (bx<96) | SSM conv/Vand frags (bx>=96) ----------------
__global__ __launch_bounds__(256) void prep_all_kernel(
    const float* __restrict__ t, const float* __restrict__ Wt, const float* __restrict__ bt,
    const float* __restrict__ Wout, const float* __restrict__ Wf,
    const float* __restrict__ bout, const float* __restrict__ bfb,
    const float* __restrict__ W1, const float* __restrict__ b1,
    const float* __restrict__ W2, const float* __restrict__ b2,
    const float* __restrict__ log_dt, const float* __restrict__ logA, const float* __restrict__ Aimg,
    const float* __restrict__ C_re, const float* __restrict__ C_im,
    float* __restrict__ tb, float* __restrict__ bc, float* __restrict__ b12,
    ushort_t* __restrict__ wcf, ushort_t* __restrict__ w12f,
    float* __restrict__ drg, float* __restrict__ dig,
    ushort_t* __restrict__ Mfrag, ushort_t* __restrict__ Vfrag)
{
    int bx = blockIdx.x, tid = threadIdx.x;
    __shared__ float trow[256];
    __shared__ float drL[64], diL[64], crL[64], ciL[64];
    __shared__ float ktab[128];
    __shared__ ushort_t bndL[128 * 128];
    if (bx < 32) {
        trow[tid] = t[bx * 256 + tid];
        __syncthreads();
        float acc = bt[tid];
        #pragma unroll 4
        for (int hh = 0; hh < 256; ++hh) acc = fmaf(trow[hh], Wt[tid * 256 + hh], acc);
        tb[bx * 256 + tid] = acc;
        return;
    }
    if (bx < 64) {
        int gt = (bx - 32) * 256 + tid;       // 0..8191
        if (gt < 256) bc[gt] = bout[gt] + bfb[gt];
        if (gt < 512) b12[gt] = (gt < 256) ? b1[gt] : b2[gt - 256];
        for (int fg = gt; fg < 9216; fg += 8192) {
            int mt = fg / 576, rem = fg % 576;
            int kc = rem >> 6, lane = rem & 63;
            int m = mt * 16 + (lane & 15);
            int kb = kc * 32 + (lane >> 4) * 8;
            #pragma unroll
            for (int j = 0; j < 8; ++j) {
                int k = kb + j;
                float v = (k < 256) ? Wout[m * 256 + k] : Wf[m * 32 + (k - 256)];
                wcf[(size_t)fg * 8 + j] = f2bf(v);
            }
        }
        return;
    }
    if (bx < 96) {
        int gt = (bx - 64) * 256 + tid;       // 0..8191
        for (int fg = gt; fg < 16384; fg += 8192) {
            int mt = fg >> 9, rem = fg & 511;
            int kc = rem >> 6, lane = rem & 63;
            int m = mt * 16 + (lane & 15);
            int kb = kc * 32 + (lane >> 4) * 8;
            #pragma unroll
            for (int j = 0; j < 8; ++j) {
                int k = kb + j;
                float v = (m < 256) ? W1[m * 256 + k] : W2[(m - 256) * 256 + k];
                w12f[(size_t)fg * 8 + j] = f2bf(v);
            }
        }
        return;
    }
    int bx2 = bx - 96;
    int h = bx2 >> 1, dir = bx2 & 1;
    if (tid < 64) {
        int n = tid;
        int idx = h * 64 + n;
        float dt = __expf(log_dt[h]);
        float Ar = -__expf(logA[idx]);
        float Ai = Aimg[idx];
        float dr = dt * Ar, di = dt * Ai;
        float er = __expf(dr);
        float wr_ = er * __cosf(di), wi_ = er * __sinf(di);
        float nr = wr_ - 1.f, ni = wi_;
        float inv = 1.f / (Ar * Ar + Ai * Ai);
        float qr = (nr * Ar + ni * Ai) * inv;
        float qi = (ni * Ar - nr * Ai) * inv;
        float cr = C_re[dir * 16384 + idx], ci = C_im[dir * 16384 + idx];
        drL[n] = dr; diL[n] = di;
        crL[n] = 2.f * (cr * qr - ci * qi);
        ciL[n] = 2.f * (cr * qi + ci * qr);
        if (dir == 0) { drg[idx] = dr; dig[idx] = di; }
    }
    __syncthreads();
    if (tid < 128) {
        int i = tid;
        float e = (float)(i + 1 - dir);
        #pragma unroll 4
        for (int n = 0; n < 64; ++n) {
            float ex = __expf(e * drL[n]);
            float ph = e * diL[n];
            float pr = ex * __cosf(ph), pi = ex * __sinf(ph);
            bndL[i * 128 + n]      = f2bf(crL[n] * pr - ciL[n] * pi);
            bndL[i * 128 + 64 + n] = f2bf(-(crL[n] * pi + ciL[n] * pr));
        }
    } else {
        int d = tid - 128;
        float e = (float)d;
        float acc = 0.f;
        #pragma unroll 4
        for (int n = 0; n < 64; ++n) {
            float ex = __expf(e * drL[n]);
            float ph = e * diL[n];
            acc += crL[n] * (ex * __cosf(ph)) - ciL[n] * (ex * __sinf(ph));
        }
        ktab[d] = acc;
    }
    __syncthreads();
    size_t base = (size_t)bx2 << 15;
    for (int idx = tid; idx < 32768; idx += 256) {
        int j = idx & 7, lane = (idx >> 3) & 63, kc = (idx >> 9) & 7, mt = idx >> 12;
        int m = mt * 16 + (lane & 15);
        int k = kc * 32 + (lane >> 4) * 8 + j;
        float v;
        if (k < 128) {
            int d = m - k - dir;
            v = (d >= 0) ? ktab[d] : 0.f;
        } else {
            v = bf2f(bndL[m * 128 + (k - 128)]);
        }
        Mfrag[base + idx] = f2bf(v);
    }
    if (dir == 0) {
        size_t vbase = (size_t)h << 14;
        for (int idx = tid; idx < 16384; idx += 256) {
            int j = idx & 7, lane = (idx >> 3) & 63, kc = (idx >> 9) & 3, mt = idx >> 11;
            int s = mt * 16 + (lane & 15);
            int k = kc * 32 + (lane >> 4) * 8 + j;
            int n = s & 63;
            float e = (float)(127 - k);
            float ex = __expf(e * drL[n]);
            float ph = e * diL[n];
            float v = (s < 64) ? ex * __cosf(ph) : ex * __sinf(ph);
            Vfrag[vbase + idx] = f2bf(v);
        }
    }
}

// ---------------- one-pass LayerNorm over H (LDS-staged tile) -> bf16 z ----------------
// block = (b, 64-l tile); xs[h][ll] in LDS, read x once.
__global__ __launch_bounds__(256) void ln1_kernel(
    const float* __restrict__ x, const float* __restrict__ tb,
    const float* __restrict__ ln_g, const float* __restrict__ ln_b,
    ushort_t* __restrict__ zbf)
{
    __shared__ float xs[256 * 64];     // 64 KiB
    __shared__ float tbg[256], lng[256], lnb[256];
    __shared__ float red[2 * 256];
    __shared__ float murs[2 * 64];
    int tid = threadIdx.x;
    int b = blockIdx.x >> 5, l0 = (blockIdx.x & 31) << 6;
    tbg[tid] = tb[b * 256 + tid];
    lng[tid] = ln_g[tid];
    lnb[tid] = ln_b[tid];
    const float* xb = x + ((size_t)b * 256) * 2048 + l0;
    for (int i = tid; i < 4096; i += 256) {
        int h = i >> 4, c4 = (i & 15) * 4;
        *(float4*)&xs[h * 64 + c4] = *(const float4*)(xb + (size_t)h * 2048 + c4);
    }
    __syncthreads();
    int c = tid & 63, w = tid >> 6;
    float sum = 0.f, ssq = 0.f;
    #pragma unroll 8
    for (int hh = 0; hh < 64; ++hh) {
        int h = w * 64 + hh;
        float v = xs[h * 64 + c] + tbg[h];
        sum += v; ssq = fmaf(v, v, ssq);
    }
    red[w * 64 + c] = sum;
    red[256 + w * 64 + c] = ssq;
    __syncthreads();
    if (tid < 64) {
        float s = red[tid] + red[64 + tid] + red[128 + tid] + red[192 + tid];
        float q = red[256 + tid] + red[320 + tid] + red[384 + tid] + red[448 + tid];
        float mean = s * (1.f / 256.f);
        float var = fmaf(q, 1.f / 256.f, -mean * mean);
        murs[tid] = mean;
        murs[64 + tid] = rsqrtf(var + 1e-5f);
    }
    __syncthreads();
    ushort_t* zb = zbf + ((size_t)b * 256) * 2048 + l0;
    for (int i = tid; i < 4096; i += 256) {
        int h = i >> 4, c4 = (i & 15) * 4;
        float g = lng[h], be = lnb[h], tbh = tbg[h];
        union { unsigned long long u; ushort_t s4[4]; } o;
        #pragma unroll
        for (int j = 0; j < 4; ++j) {
            int cc = c4 + j;
            float v = xs[h * 64 + cc] + tbh;
            o.s4[j] = f2bf((v - murs[cc]) * murs[64 + cc] * g + be);
        }
        *(unsigned long long*)(zb + (size_t)h * 2048 + c4) = o.u;
    }
}

// ---------------- mega SSM: z -> Q (MFMA) -> in-LDS scan -> conv (MFMA) -> gelu -> ya ----------------
__global__ __launch_bounds__(256) void ssm_mega_kernel(
    const ushort_t* __restrict__ zbf,
    const float* __restrict__ drg, const float* __restrict__ dig, const float* __restrict__ Dv,
    const ushort_t* __restrict__ Mfrag, const ushort_t* __restrict__ Vfrag,
    ushort_t* __restrict__ ya)
{
    __shared__ ushort_t Zs[64 * 136];
    __shared__ ushort_t Ssf[64 * 136];
    __shared__ ushort_t Ssb[64 * 136];
    __shared__ float Qb[2 * 128 * 17];
    int tid = threadIdx.x, lane = tid & 63, w = tid >> 6;
    int q = lane >> 4, cl = lane & 15;
    int h = blockIdx.x, cb = blockIdx.y;
    int b0 = cb * 4;
    for (int i = tid; i < 1024; i += 256) {
        int bsub = i >> 8, t8 = (i & 255) * 8;
        const ushort_t* zrow = zbf + ((size_t)((b0 + bsub) * 256 + h) << 11);
        *(uint4v*)&Zs[(bsub * 16 + (t8 >> 7)) * 136 + (t8 & 127)] = *(const uint4v*)(zrow + t8);
    }
    float dr0 = drg[h * 64 + lane], di0 = dig[h * 64 + lane];
    float ex128 = __expf(128.f * dr0);
    float w128r = ex128 * __cosf(128.f * di0);
    float w128i = ex128 * __sinf(128.f * di0);
    float Dh = Dv[h];
    __syncthreads();
    const ushort_t* vbase = Vfrag + ((size_t)h << 14);
    const ushort_t* mbase0 = Mfrag + ((size_t)(h * 2) << 15);
    const ushort_t* mbase1 = Mfrag + ((size_t)(h * 2 + 1) << 15);
    for (int bsub = 0; bsub < 4; ++bsub) {
        f32x4 qa[2][2] = {};
        #pragma unroll
        for (int kc = 0; kc < 4; ++kc) {
            int kk = kc * 32 + q * 8;
            bf16x8 bz = __builtin_bit_cast(bf16x8,
                *(const uint4v*)&Zs[(bsub * 16 + cl) * 136 + kk]);
            bf16x8 bzr = __builtin_bit_cast(bf16x8, rev8v(
                *(const uint4v*)&Zs[(bsub * 16 + (15 - cl)) * 136 + (120 - kk)]));
            #pragma unroll
            for (int i = 0; i < 2; ++i) {
                int mt = w * 2 + i;
                bf16x8 af = __builtin_bit_cast(bf16x8,
                    *(const uint4v*)(vbase + (((mt * 4 + kc) * 64 + lane) << 3)));
                qa[0][i] = __builtin_amdgcn_mfma_f32_16x16x32_bf16(af, bz, qa[0][i], 0, 0, 0);
                qa[1][i] = __builtin_amdgcn_mfma_f32_16x16x32_bf16(af, bzr, qa[1][i], 0, 0, 0);
            }
        }
        __syncthreads();
        #pragma unroll
        for (int d = 0; d < 2; ++d)
            #pragma unroll
            for (int i = 0; i < 2; ++i) {
                int mt = w * 2 + i;
                #pragma unroll
                for (int r = 0; r < 4; ++r)
                    Qb[d * 2176 + (mt * 16 + q * 4 + r) * 17 + cl] = qa[d][i][r];
            }
        __syncthreads();
        if (w < 2) {
            ushort_t* S = (w == 0) ? Ssf : Ssb;
            const float* Qp = Qb + w * 2176;
            float sre = 0.f, sim = 0.f;
            for (int cc = 0; cc < 16; ++cc) {
                S[(bsub * 16 + cc) * 136 + lane] = f2bf(sre);
                S[(bsub * 16 + cc) * 136 + 64 + lane] = f2bf(sim);
                float qre = Qp[lane * 17 + cc];
                float qim = Qp[(64 + lane) * 17 + cc];
                float nre = fmaf(w128r, sre, fmaf(-w128i, sim, qre));
                float nim = fmaf(w128r, sim, fmaf(w128i, sre, qim));
                sre = nre; sim = nim;
            }
        }
        __syncthreads();
    }
    f32x4 accf[2][4] = {}, accb[2][4] = {};
    for (int kc = 0; kc < 8; ++kc) {
        int kk = (kc & 3) * 32 + q * 8;
        bf16x8 aff[2], afb[2];
        #pragma unroll
        for (int i = 0; i < 2; ++i) {
            int mt = w * 2 + i;
            aff[i] = __builtin_bit_cast(bf16x8, *(const uint4v*)(mbase0 + (((mt * 8 + kc) * 64 + lane) << 3)));
            afb[i] = __builtin_bit_cast(bf16x8, *(const uint4v*)(mbase1 + (((mt * 8 + kc) * 64 + lane) << 3)));
        }
        #pragma unroll
        for (int nt = 0; nt < 4; ++nt) {
            bf16x8 bff, bfb_;
            if (kc < 4) {
                bff  = __builtin_bit_cast(bf16x8, *(const uint4v*)&Zs[(nt * 16 + cl) * 136 + kk]);
                bfb_ = __builtin_bit_cast(bf16x8, rev8v(
                       *(const uint4v*)&Zs[(nt * 16 + (15 - cl)) * 136 + (120 - kk)]));
            } else {
                bff  = __builtin_bit_cast(bf16x8, *(const uint4v*)&Ssf[(nt * 16 + cl) * 136 + kk]);
                bfb_ = __builtin_bit_cast(bf16x8, *(const uint4v*)&Ssb[(nt * 16 + cl) * 136 + kk]);
            }
            #pragma unroll
            for (int i = 0; i < 2; ++i) {
                accf[i][nt] = __builtin_amdgcn_mfma_f32_16x16x32_bf16(aff[i], bff,  accf[i][nt], 0, 0, 0);
                accb[i][nt] = __builtin_amdgcn_mfma_f32_16x16x32_bf16(afb[i], bfb_, accb[i][nt], 0, 0, 0);
            }
        }
    }
    __syncthreads();
    ushort_t* Yf = Ssf;
    ushort_t* Yb = Ssb;
    #pragma unroll
    for (int i = 0; i < 2; ++i) {
        int mt = w * 2 + i;
        #pragma unroll
        for (int nt = 0; nt < 4; ++nt) {
            int col = nt * 16 + cl;
            #pragma unroll
            for (int r = 0; r < 4; ++r) {
                int m = mt * 16 + q * 4 + r;
                Yf[col * 136 + m] = f2bf(accf[i][nt][r]);
                Yb[col * 136 + m] = f2bf(accb[i][nt][r]);
            }
        }
    }
    __syncthreads();
    for (int u = tid; u < 1024; u += 256) {
        int col = u >> 4, i0 = (u & 15) * 8;
        int bsub = col >> 4, c = col & 15;
        int colb = bsub * 16 + (15 - c);
        union { uint4v v; ushort_t s8[8]; } uf, uz, ub, uo;
        uf.v = *(const uint4v*)&Yf[col * 136 + i0];
        uz.v = *(const uint4v*)&Zs[col * 136 + i0];
        ub.v = rev8v(*(const uint4v*)&Yb[colb * 136 + (120 - i0)]);
        #pragma unroll
        for (int j = 0; j < 8; ++j) {
            float v = bf2f(uf.s8[j]) + bf2f(ub.s8[j]) + Dh * bf2f(uz.s8[j]);
            uo.s8[j] = f2bf(gelu_tanh(v));
        }
        ushort_t* yrow = ya + ((size_t)((b0 + bsub) * 256 + h) << 11);
        *(uint4v*)(yrow + c * 128 + i0) = uo.v;
    }
}

// ---------------- fused GEMM12: u = Wc@[ya;feat]+bc+tb+x; g=gate(u) in LDS; o1=W1@g+b1+x, o2=W2@g+b2 ----------------
__global__ __launch_bounds__(256, 2) void gemm12_kernel(
    const ushort_t* __restrict__ ya, const float* __restrict__ feat,
    const float* __restrict__ x, const float* __restrict__ tb,
    const float* __restrict__ bc, const float* __restrict__ b12,
    const ushort_t* __restrict__ wcf, const ushort_t* __restrict__ w12f,
    float* __restrict__ out)
{
    __shared__ __align__(16) ushort_t XT[64 * 48];    // staging transpose, k-contig
    __shared__ __align__(16) ushort_t GT[64 * 264];   // g tile [col 64][h 256 +8 pad]
    int tid = threadIdx.x;
    int w = tid >> 6, lane = tid & 63;
    int q = lane >> 4, nl = lane & 15;
    int b = blockIdx.x >> 5;
    int l0 = (blockIdx.x & 31) << 6;
    const float* xb = x + ((size_t)b * 256) * 2048 + l0;
    // ---- G1: acc1 = Wc @ [ya; feat] ----
    f32x4 acc1[4][4] = {};
    int kk = tid >> 3, ng = tid & 7;
    for (int kc = 0; kc < 9; ++kc) {
        int k = kc * 32 + kk;
        union { uint4v v; ushort_t s[8]; } u;
        if (k < 256) {
            u.v = *(const uint4v*)(ya + ((size_t)(b * 256 + k) << 11) + l0 + ng * 8);
        } else {
            const float* src = feat + (size_t)(b * 32 + (k - 256)) * 2048 + l0 + ng * 8;
            #pragma unroll
            for (int j = 0; j < 8; ++j) u.s[j] = f2bf(src[j]);
        }
        #pragma unroll
        for (int j = 0; j < 8; ++j) XT[(ng * 8 + j) * 48 + kk] = u.s[j];
        __syncthreads();
        bf16x8 af[4], bfr[4];
        #pragma unroll
        for (int i = 0; i < 4; ++i) {
            const ushort_t* p = wcf + ((size_t)((w * 4 + i) * 9 + kc) * 64 + lane) * 8;
            af[i] = __builtin_bit_cast(bf16x8, *(const uint4v*)p);
        }
        #pragma unroll
        for (int nt = 0; nt < 4; ++nt) {
            const ushort_t* p = &XT[(nt * 16 + nl) * 48 + q * 8];
            bfr[nt] = __builtin_bit_cast(bf16x8, *(const uint4v*)p);
        }
        #pragma unroll
        for (int i = 0; i < 4; ++i)
            #pragma unroll
            for (int nt = 0; nt < 4; ++nt)
                acc1[i][nt] = __builtin_amdgcn_mfma_f32_16x16x32_bf16(af[i], bfr[nt], acc1[i][nt], 0, 0, 0);
        __syncthreads();
    }
    // ---- epilogue A: g = gate(acc1 + bc + tb + x) -> GT[col][m] ----
    #pragma unroll
    for (int i = 0; i < 4; ++i) {
        #pragma unroll
        for (int nt = 0; nt < 4; ++nt) {
            int c = nt * 16 + nl;
            #pragma unroll
            for (int r = 0; r < 4; ++r) {
                int m = (w * 4 + i) * 16 + q * 4 + r;
                float v = acc1[i][nt][r] + bc[m] + tb[b * 256 + m] + xb[(size_t)m * 2048 + c];
                GT[c * 264 + m] = f2bf(gate_fn(v));
            }
        }
    }
    __syncthreads();
    // ---- G2: acc2 = [W1;W2] @ g  (sync-free) ----
    f32x4 acc2[8][4] = {};
    for (int kc = 0; kc < 8; ++kc) {
        bf16x8 af[8], bfr[4];
        #pragma unroll
        for (int i = 0; i < 8; ++i) {
            int mt = w * 8 + i;
            const ushort_t* p = w12f + ((size_t)(mt * 8 + kc) * 64 + lane) * 8;
            af[i] = __builtin_bit_cast(bf16x8, *(const uint4v*)p);
        }
        #pragma unroll
        for (int nt = 0; nt < 4; ++nt) {
            const ushort_t* p = &GT[(nt * 16 + nl) * 264 + kc * 32 + q * 8];
            bfr[nt] = __builtin_bit_cast(bf16x8, *(const uint4v*)p);
        }
        #pragma unroll
        for (int i = 0; i < 8; ++i)
            #pragma unroll
            for (int nt = 0; nt < 4; ++nt)
                acc2[i][nt] = __builtin_amdgcn_mfma_f32_16x16x32_bf16(af[i], bfr[nt], acc2[i][nt], 0, 0, 0);
    }
    // ---- epilogue B: o1 = acc2(+x), o2 ----
    #pragma unroll
    for (int i = 0; i < 8; ++i) {
        int mt = w * 8 + i;
        #pragma unroll
        for (int nt = 0; nt < 4; ++nt) {
            int n = l0 + nt * 16 + nl;
            int c = nt * 16 + nl;
            #pragma unroll
            for (int r = 0; r < 4; ++r) {
                int m2 = mt * 16 + q * 4 + r;
                float v = acc2[i][nt][r] + b12[m2];
                if (m2 < 256) {
                    out[(size_t)(b * 256 + m2) * 2048 + n] = v + xb[(size_t)m2 * 2048 + c];
                } else {
                    out[(size_t)BHL + (size_t)(b * 256 + (m2 - 256)) * 2048 + n] = v;
                }
            }
        }
    }
}

extern "C" void kernel_launch(void* const* d_in, const int* in_sizes, int n_in,
                              void* d_out, int out_size, void* d_ws, size_t ws_size,
                              hipStream_t stream) {
    const float* x      = (const float*)d_in[0];
    const float* t      = (const float*)d_in[1];
    const float* feat   = (const float*)d_in[2];
    const float* Wt     = (const float*)d_in[3];
    const float* bt     = (const float*)d_in[4];
    const float* ln_g   = (const float*)d_in[5];
    const float* ln_b   = (const float*)d_in[6];
    const float* log_dt = (const float*)d_in[7];
    const float* logA   = (const float*)d_in[8];
    const float* Aimg   = (const float*)d_in[9];
    const float* C_re   = (const float*)d_in[10];
    const float* C_im   = (const float*)d_in[11];
    const float* Dv     = (const float*)d_in[12];
    const float* Wout   = (const float*)d_in[13];
    const float* bout   = (const float*)d_in[14];
    const float* W1     = (const float*)d_in[15];
    const float* b1     = (const float*)d_in[16];
    const float* W2     = (const float*)d_in[17];
    const float* b2     = (const float*)d_in[18];
    const float* Wf     = (const float*)d_in[19];
    const float* bfb    = (const float*)d_in[20];

    // d_out (128 MiB): zbf [0,32Mi) scratch, dead before gemm12 writes out.
    char* ob = (char*)d_out;
    ushort_t* zbf = (ushort_t*)ob;
    float*    out = (float*)d_out;

    // ws (512 MiB): Mfrag [0,32Mi) | Vfrag [32,40Mi) | ya [40,72Mi) | tables
    char* ws = (char*)d_ws;
    ushort_t* Mfrag = (ushort_t*)ws;
    ushort_t* Vfrag = (ushort_t*)(ws + 33554432);
    ushort_t* yab   = (ushort_t*)(ws + 41943040);
    char* ws2 = ws + 75497472;
    float* tb   = (float*)ws2;
    float* drg  = (float*)(ws2 + 32768);
    float* dig  = (float*)(ws2 + 98304);
    float* bc   = (float*)(ws2 + 163840);
    float* b12  = (float*)(ws2 + 164864);
    ushort_t* wcf  = (ushort_t*)(ws2 + 166912);
    ushort_t* w12f = (ushort_t*)(ws2 + 314368);

    prep_all_kernel<<<608, 256, 0, stream>>>(t, Wt, bt, Wout, Wf, bout, bfb, W1, b1, W2, b2,
                                             log_dt, logA, Aimg, C_re, C_im,
                                             tb, bc, b12, wcf, w12f, drg, dig, Mfrag, Vfrag);
    ln1_kernel<<<1024, 256, 0, stream>>>(x, tb, ln_g, ln_b, zbf);
    ssm_mega_kernel<<<dim3(256, 8), 256, 0, stream>>>(zbf, drg, dig, Dv, Mfrag, Vfrag, yab);
    gemm12_kernel<<<1024, 256, 0, stream>>>(yab, feat, x, tb, bc, b12, wcf, w12f, out);
}